// Round 1
// 103.903 us; speedup vs baseline: 1.0029x; 1.0029x over previous
//
#include <hip/hip_runtime.h>

#define NEG  (-1e30f)
#define LN2F 0.69314718056f

// Problem dims (fixed by setup_inputs): B=16, TXT=128, MEL=512, NM=80
#define B_   16
#define TXT_ 128
#define MEL_ 512
#define NM_  80
#define IT_  8     // i-rows per lp block

typedef float vf2 __attribute__((ext_vector_type(2)));

// ---------------------------------------------------------------------------
// Kernel 1: log_prob_matrix (proven since R3). Also zeroes out[0] and the
// per-b musum stash wT[b][0][0] (wt_kernel atomicAdds into it later).
// ---------------------------------------------------------------------------
__global__ __launch_bounds__(512) void lp_kernel(
    const float* __restrict__ mu_logvar,  // (B, TXT, 2*NM)
    const float* __restrict__ melspec,    // (B, NM, MEL)
    float* __restrict__ lp_out,           // (B, TXT, MEL)  = d_out + 1
    float* __restrict__ wT,               // (B, MEL, TXT) in ws (stash zero)
    float* __restrict__ out0)             // d_out[0]
{
    const int i0 = blockIdx.x * IT_;
    const int b  = blockIdx.y;
    const int t  = threadIdx.x;

    __shared__ float2 s_wb[IT_][NM_];
    __shared__ float  s_cp[IT_ * NM_];
    __shared__ float  s_cc[IT_];

    for (int u = t; u < IT_ * NM_; u += 512) {   // 640 > 512: strided loop!
        int ii = u / NM_;
        int n  = u - ii * NM_;
        const float* row = mu_logvar + (size_t)(b * TXT_ + i0 + ii) * (2 * NM_);
        float mu = row[n];
        float lv = row[NM_ + n];
        float w  = __expf(-lv);
        s_wb[ii][n] = make_float2(w, -2.f * mu * w);
        s_cp[u]     = mu * mu * w + lv;
    }
    __syncthreads();
    if (t < IT_) {
        float c = 0.f;
        #pragma unroll
        for (int n = 0; n < NM_; ++n) c += s_cp[t * NM_ + n];
        s_cc[t] = c;
    }
    __syncthreads();

    const float* xcol = melspec + (size_t)b * NM_ * MEL_ + t;
    float acc[IT_];
    #pragma unroll
    for (int ii = 0; ii < IT_; ++ii) acc[ii] = 0.f;

    #pragma unroll 4
    for (int n = 0; n < NM_; ++n) {
        float x  = xcol[(size_t)n * MEL_];
        float x2 = x * x;
        #pragma unroll
        for (int ii = 0; ii < IT_; ++ii) {
            float2 wb = s_wb[ii][n];
            acc[ii] = fmaf(wb.x, x2, fmaf(wb.y, x, acc[ii]));
        }
    }

    const size_t rowbase = ((size_t)(b * TXT_ + i0)) * MEL_ + t;
    #pragma unroll
    for (int ii = 0; ii < IT_; ++ii) {
        lp_out[rowbase + (size_t)ii * MEL_] =
            (-0.5f / (float)NM_) * (acc[ii] + s_cc[ii]);
    }

    if (i0 == 0 && t == 0) wT[(size_t)b * MEL_ * TXT_] = 0.f;  // stash = 0
    if (i0 == 0 && b == 0 && t == 0) *out0 = 0.f;
}

// ---------------------------------------------------------------------------
// Kernel 2: fused shift + exp + transpose (R11).
//   mu_t = max_i lp[b][i][t];  wT[b][t][i] = exp(lp[b][i][t] - mu_t - ln2)
//   stash wT[b][0][0] += sum_{t in [1,TendM1]}(mu_t+ln2)  (+ lp00 from t0=0)
// The mu-shift is LOAD-BEARING (R10 post-mortem): w <= 1/2 keeps the max
// column's per-step factor ~1, so lagging columns never hit flush-to-zero
// between the scan's renorms. Block = 128x32 (i x t) LDS slab; reads and
// writes both coalesced; global row t=0 of wT is left as the stash row
// (scan only reads rows 1..511).
// ---------------------------------------------------------------------------
__global__ __launch_bounds__(256) void wt_kernel(
    const float* __restrict__ lp,   // (B, TXT, MEL) = d_out + 1
    const int* __restrict__ mel_len,
    float* __restrict__ wT)         // (B, MEL, TXT) in ws
{
    __shared__ float tileT[32][TXT_ + 1];   // [t_loc][i], pad breaks conflicts
    __shared__ float pmax[32][8];
    __shared__ float psum[32];

    const int t0  = blockIdx.x * 32;   // mel tile
    const int b   = blockIdx.y;
    const int tid = threadIdx.x;       // 0..255

    const float* src = lp + (size_t)b * TXT_ * MEL_ + t0;
    for (int u = tid; u < TXT_ * 32; u += 256) {
        int i = u >> 5, c = u & 31;
        tileT[c][i] = src[(size_t)i * MEL_ + c];
    }
    __syncthreads();

    {   // 8-way partial max over i per t_loc
        int tt = tid >> 3, g = tid & 7;
        float m = NEG;
        #pragma unroll
        for (int k = 0; k < 16; ++k) m = fmaxf(m, tileT[tt][g * 16 + k]);
        pmax[tt][g] = m;
    }
    __syncthreads();
    if (tid < 32) {
        float m = pmax[tid][0];
        #pragma unroll
        for (int g = 1; g < 8; ++g) m = fmaxf(m, pmax[tid][g]);
        pmax[tid][0] = m;                          // mu_t
        int tg = t0 + tid;
        int TendM1 = mel_len[b] - 1;
        psum[tid] = (tg >= 1 && tg <= TendM1) ? (m + LN2F) : 0.f;
    }
    __syncthreads();

    float* dstb = wT + (size_t)b * MEL_ * TXT_;
    for (int u = tid; u < 32 * TXT_; u += 256) {
        int tt = u >> 7, i = u & 127;
        int tg = t0 + tt;
        if (tg != 0)   // keep global row 0 as the stash row
            dstb[(size_t)tg * TXT_ + i] =
                __expf(tileT[tt][i] - pmax[tt][0] - LN2F);
    }

    if (tid == 0) {
        float s = 0.f;
        #pragma unroll
        for (int k = 0; k < 32; ++k) s += psum[k];
        if (t0 == 0) s += tileT[0][0];             // + lp[b][0][0]
        atomicAdd(&dstb[0], s);                    // musum stash
    }
}

// ---------------------------------------------------------------------------
// Kernel 3: linear-domain scan (R10 machinery + R9 numerics).
//   s[t][j] = (s[t-1][j] + s[t-1][j-1]) * w[t][j],  w <= 1/2 (pre-exp'd!)
// Lane l owns cols j0=2l, j1=2l+1. Chain/step = DPP wave_shr1 + add + mul;
// NO transcendentals in-loop. This round: the pipeline is deepened from 16
// to 48 in-flight rows (vmcnt(12) -> vmcnt(44)). Rationale: the scan is
// LATENCY-bound — wT rows were written by other XCDs so reads come from
// L3/HBM (~450-900 cy); a 12-load lead (~240 cy) stalls every group.
// 44-load lead (~700+ cy) covers it; per-step rate drops to the ~16-20 cy
// compute chain. Renorm cadence stays every 16 steps (load-bearing);
// refill clamp min(t_pf, MEL-1) keeps loads in-bounds, and steps past
// TendM1 occur strictly after the fin latch (Tend<=512 => TendM1<=511,
// and row 511 is still loaded exactly), so the consumed prefix is
// bit-identical to the 16-deep version.
// ---------------------------------------------------------------------------
__device__ __forceinline__ float dpp_shr1_zero(float x) {
    int r = __builtin_amdgcn_update_dpp(
        0, __builtin_bit_cast(int, x), 0x138 /*wave_shr:1*/, 0xf, 0xf, false);
    return __builtin_bit_cast(float, r);
}

#define DPPMAX(M, CTRL, RM)                                               \
    do {                                                                  \
        int _t = __builtin_amdgcn_update_dpp(                             \
            __builtin_bit_cast(int, M), __builtin_bit_cast(int, M),       \
            CTRL, RM, 0xf, false);                                        \
        M = fmaxf(M, __builtin_bit_cast(float, _t));                      \
    } while (0)

#define GLOAD2(DST, PTR) \
    asm volatile("global_load_dwordx2 %0, %1, off" : "=v"(DST) : "v"(PTR))
#define VWAIT44(A,B,C,D2) \
    asm volatile("s_waitcnt vmcnt(44)" : "+v"(A), "+v"(B), "+v"(C), "+v"(D2))

__global__ __launch_bounds__(64) void scan_kernel(
    const float* __restrict__ wT,          // (B, MEL, TXT) in ws
    const int* __restrict__ text_len, const int* __restrict__ mel_len,
    float* __restrict__ out0)
{
    const int b = blockIdx.x;
    const int l = threadIdx.x;
    const float* base = wT + (size_t)b * MEL_ * TXT_;
    const float* wb_  = base + 2 * l;                 // lane column ptr
    const int Tend = mel_len[b], TendM1 = Tend - 1;   // Tend in [256,512]

    float s0 = (l == 0) ? 1.f : 0.f;   // s[t][j0]
    float s1 = 0.f;                    // s[t][j1]
    float fin0 = 0.f, fin1 = 0.f;
    int   shift_acc = 0, fsh = 0;
    int   t_cur = 1;
    int   t_pf  = 49;                  // next refill row (48-deep pipeline)

    vf2 q0,q1,q2,q3,q4,q5,q6,q7,q8,q9,q10,q11,q12,q13,q14,q15,
        q16,q17,q18,q19,q20,q21,q22,q23,q24,q25,q26,q27,q28,q29,q30,q31,
        q32,q33,q34,q35,q36,q37,q38,q39,q40,q41,q42,q43,q44,q45,q46,q47;
    {
        const float* p;
        #define INIT(Q, ROW) p = wb_ + (size_t)(ROW) * TXT_; GLOAD2(Q, p)
        INIT(q0,1);   INIT(q1,2);   INIT(q2,3);   INIT(q3,4);
        INIT(q4,5);   INIT(q5,6);   INIT(q6,7);   INIT(q7,8);
        INIT(q8,9);   INIT(q9,10);  INIT(q10,11); INIT(q11,12);
        INIT(q12,13); INIT(q13,14); INIT(q14,15); INIT(q15,16);
        INIT(q16,17); INIT(q17,18); INIT(q18,19); INIT(q19,20);
        INIT(q20,21); INIT(q21,22); INIT(q22,23); INIT(q23,24);
        INIT(q24,25); INIT(q25,26); INIT(q26,27); INIT(q27,28);
        INIT(q28,29); INIT(q29,30); INIT(q30,31); INIT(q31,32);
        INIT(q32,33); INIT(q33,34); INIT(q34,35); INIT(q35,36);
        INIT(q36,37); INIT(q37,38); INIT(q38,39); INIT(q39,40);
        INIT(q40,41); INIT(q41,42); INIT(q42,43); INIT(q43,44);
        INIT(q44,45); INIT(q45,46); INIT(q46,47); INIT(q47,48);
        #undef INIT
    }

    #define STEP(Q)                                          \
        do {                                                 \
            float nb  = dpp_shr1_zero(s1);                   \
            float ns0 = (s0 + nb) * (Q).x;                   \
            float ns1 = (s1 + s0) * (Q).y;                   \
            bool hit = (t_cur == TendM1);                    \
            fin0 = hit ? ns0 : fin0;                         \
            fin1 = hit ? ns1 : fin1;                         \
            fsh  = hit ? shift_acc : fsh;                    \
            s0 = ns0; s1 = ns1; ++t_cur;                     \
        } while (0)

    #define REFILL(Q)                                        \
        do {                                                 \
            int rr = min(t_pf, MEL_ - 1);                    \
            const float* p_ = wb_ + (size_t)rr * TXT_;       \
            GLOAD2(Q, p_);                                   \
            ++t_pf;                                          \
        } while (0)

    #define GROUP(QA,QB,QC,QD)                               \
        do {                                                 \
            VWAIT44(QA,QB,QC,QD);                            \
            STEP(QA); STEP(QB); STEP(QC); STEP(QD);          \
            REFILL(QA); REFILL(QB); REFILL(QC); REFILL(QD);  \
        } while (0)

    // exact power-of-2 renorm (wave-uniform), every 16 steps
    #define RENORM16()                                                    \
        do {                                                              \
            float mm = fmaxf(s0, s1);                                     \
            DPPMAX(mm, 0x111, 0xf);   /* row_shr:1  */                    \
            DPPMAX(mm, 0x112, 0xf);   /* row_shr:2  */                    \
            DPPMAX(mm, 0x114, 0xf);   /* row_shr:4  */                    \
            DPPMAX(mm, 0x118, 0xf);   /* row_shr:8  */                    \
            DPPMAX(mm, 0x142, 0xa);   /* row_bcast:15 -> rows 1,3 */      \
            DPPMAX(mm, 0x143, 0xc);   /* row_bcast:31 -> rows 2,3 */      \
            float M = __builtin_bit_cast(                                 \
                float, __builtin_amdgcn_readlane(                         \
                           __builtin_bit_cast(int, mm), 63));             \
            if (M > 0.f) {                                                \
                int e;                                                    \
                (void)frexpf(M, &e);                                      \
                float sc = ldexpf(1.f, -e);                               \
                s0 *= sc; s1 *= sc;                                       \
                shift_acc += e;                                           \
            }                                                             \
        } while (0)

    for (int t0 = 1; t0 <= TendM1; t0 += 48) {
        GROUP(q0,q1,q2,q3);     GROUP(q4,q5,q6,q7);
        GROUP(q8,q9,q10,q11);   GROUP(q12,q13,q14,q15);
        RENORM16();
        GROUP(q16,q17,q18,q19); GROUP(q20,q21,q22,q23);
        GROUP(q24,q25,q26,q27); GROUP(q28,q29,q30,q31);
        RENORM16();
        GROUP(q32,q33,q34,q35); GROUP(q36,q37,q38,q39);
        GROUP(q40,q41,q42,q43); GROUP(q44,q45,q46,q47);
        RENORM16();
    }
    #undef STEP
    #undef REFILL
    #undef GROUP
    #undef RENORM16

    int jstar = text_len[b] - 1;                   // in [63,127]
    float vs = (jstar & 1) ? fin1 : fin0;
    int   vh = fsh;
    vs = __shfl(vs, jstar >> 1);
    vh = __shfl(vh, jstar >> 1);
    if (l == 0) {
        float musum = base[0];                     // wt_kernel stash
        float val   = __logf(vs) + (float)vh * LN2F + musum;
        atomicAdd(out0, -(val / (float)Tend) * (1.f / (float)B_));
    }
}

// ---------------------------------------------------------------------------
extern "C" void kernel_launch(void* const* d_in, const int* in_sizes, int n_in,
                              void* d_out, int out_size, void* d_ws, size_t ws_size,
                              hipStream_t stream) {
    const float* mu_logvar = (const float*)d_in[0];
    const float* melspec   = (const float*)d_in[1];
    const int*   text_len  = (const int*)d_in[2];
    const int*   mel_len   = (const int*)d_in[3];

    float* out    = (float*)d_out;      // out[0] = mdn_loss, out[1..] = lp
    float* lp_out = out + 1;
    float* wT     = (float*)d_ws;       // 4 MB transposed shifted-exp weights

    dim3 g1(TXT_ / IT_, B_);
    lp_kernel<<<g1, MEL_, 0, stream>>>(mu_logvar, melspec, lp_out, wT, out);
    dim3 g2(MEL_ / 32, B_);
    wt_kernel<<<g2, 256, 0, stream>>>(lp_out, mel_len, wT);
    scan_kernel<<<B_, 64, 0, stream>>>(wT, text_len, mel_len, out);
}